// Round 4
// baseline (957.165 us; speedup 1.0000x reference)
//
#include <hip/hip_runtime.h>
#include <math.h>

#define NN 50000
#define EN 200000
#define CC 4
#define HH 128
#define GG 64
#define LDSA 136  // bf16 row stride (+8 pad keeps 16B alignment, rotates bank groups)
#define LDSF 132  // f32 row stride for fused-pool tile

typedef __attribute__((ext_vector_type(8))) short bs8;
typedef __attribute__((ext_vector_type(4))) float f32x4;

__device__ __forceinline__ unsigned short f2bf(float f) {
  unsigned int u = __float_as_uint(f);
  u += 0x7FFFu + ((u >> 16) & 1u);
  return (unsigned short)(u >> 16);
}
__device__ __forceinline__ float bf2f(unsigned short h) {
  return __uint_as_float(((unsigned int)h) << 16);
}
// fast erf-GELU: A&S 7.1.26 minimax (|erf err| ~1.5e-7) + hw rcp/exp
__device__ __forceinline__ float gelu_f(float x) {
  float z = fabsf(x) * 0.7071067811865476f;
  float t = __builtin_amdgcn_rcpf(fmaf(0.3275911f, z, 1.0f));
  float poly = t * fmaf(t, fmaf(t, fmaf(t, fmaf(t, 1.061405429f, -1.453152027f),
                                        1.421413741f), -0.284496736f), 0.254829592f);
  float e = fmaf(-poly, __expf(-z * z), 1.0f);
  return 0.5f * x * (1.0f + copysignf(e, x));
}

// ---------------- CSR build ----------------
__global__ __launch_bounds__(256) void count_kernel(const int* __restrict__ dst,
                                                    int* __restrict__ counts) {
  int e = blockIdx.x * 256 + threadIdx.x;
  if (e < EN) atomicAdd(&counts[dst[e]], 1);
}

__global__ __launch_bounds__(256) void block_sum_kernel(const int* __restrict__ counts,
                                                        int* __restrict__ bsums) {
  int tid = threadIdx.x;
  int i = blockIdx.x * 256 + tid;
  int v = (i < NN) ? counts[i] : 0;
#pragma unroll
  for (int d = 1; d < 64; d <<= 1) v += __shfl_xor(v, d);
  __shared__ int ws4[4];
  if ((tid & 63) == 0) ws4[tid >> 6] = v;
  __syncthreads();
  if (tid == 0) bsums[blockIdx.x] = ws4[0] + ws4[1] + ws4[2] + ws4[3];
}

__global__ __launch_bounds__(256) void bsum_scan_kernel(const int* __restrict__ bsums,
                                                        int* __restrict__ boffs, int nb) {
  int tid = threadIdx.x, lane = tid & 63, wv = tid >> 6;
  int v = (tid < nb) ? bsums[tid] : 0;
  int s = v;
#pragma unroll
  for (int d = 1; d < 64; d <<= 1) { int t = __shfl_up(s, d); if (lane >= d) s += t; }
  __shared__ int wsum[4];
  if (lane == 63) wsum[wv] = s;
  __syncthreads();
  int pre = 0;
  for (int j = 0; j < wv; ++j) pre += wsum[j];
  if (tid < nb) boffs[tid] = pre + s - v;
}

__global__ __launch_bounds__(256) void block_scan_kernel(const int* __restrict__ counts,
                                                         const int* __restrict__ boffs,
                                                         int* __restrict__ offsets,
                                                         int* __restrict__ cursor) {
  int tid = threadIdx.x, lane = tid & 63, wv = tid >> 6;
  int i = blockIdx.x * 256 + tid;
  int v = (i < NN) ? counts[i] : 0;
  int s = v;
#pragma unroll
  for (int d = 1; d < 64; d <<= 1) { int t = __shfl_up(s, d); if (lane >= d) s += t; }
  __shared__ int wsum[4];
  if (lane == 63) wsum[wv] = s;
  __syncthreads();
  int pre = boffs[blockIdx.x];
  for (int j = 0; j < wv; ++j) pre += wsum[j];
  if (i < NN) { int e = pre + s - v; offsets[i] = e; cursor[i] = e; }
  if (i == 0) offsets[NN] = EN;
}

__global__ __launch_bounds__(256) void fill_kernel(const int* __restrict__ dst,
                                                   int* __restrict__ cursor,
                                                   int* __restrict__ csr_e) {
  int e = blockIdx.x * 256 + threadIdx.x;
  if (e < EN) {
    int pos = atomicAdd(&cursor[dst[e]], 1);
    csr_e[pos] = e;
  }
}

// ---------------- weight prep: transpose + hi/lo bf16 split (all 6 matrices) ------
__global__ __launch_bounds__(256) void prep_w_kernel(const float* __restrict__ W1,
                                                     const float* __restrict__ W2,
                                                     const float* __restrict__ Wm1,
                                                     const float* __restrict__ Wm2,
                                                     unsigned short* __restrict__ wts) {
  int m = blockIdx.x >> 6;
  int idx = (blockIdx.x & 63) * 256 + threadIdx.x;  // 0..16383
  const float* src = (m == 0) ? W1 : (m == 1) ? W1 + 16384 : (m == 2) ? W2
                     : (m == 3) ? W2 + 16384 : (m == 4) ? Wm1 : Wm2;
  unsigned short* dhi = wts + m * 32768;
  unsigned short* dlo = dhi + 16384;
  int n = idx >> 7, k = idx & 127;
  float v = src[k * HH + n];  // src [k][n] -> dst [n][k]
  unsigned short hi = f2bf(v);
  dhi[n * HH + k] = hi;
  dlo[n * HH + k] = f2bf(v - bf2f(hi));
}

// ---------------- bond encoder: 16 edges per block ----------------
__global__ __launch_bounds__(256) void ee_kernel(const float* __restrict__ eattr,
                                                 const float* __restrict__ Wbe,
                                                 const float* __restrict__ bbe,
                                                 float* __restrict__ ee) {
  __shared__ float Ws[16 * HH];
  __shared__ float Ea[16 * 16];
  int tid = threadIdx.x;
  int e0 = blockIdx.x * 16;
#pragma unroll
  for (int i = 0; i < 8; ++i) Ws[tid + i * 256] = Wbe[tid + i * 256];
  Ea[tid] = eattr[(size_t)e0 * 16 + tid];
  __syncthreads();
  int h = tid & 127, half = tid >> 7;
  float bb = bbe[h];
#pragma unroll
  for (int j = 0; j < 8; ++j) {
    int el = j * 2 + half;
    float acc = bb;
#pragma unroll
    for (int d = 0; d < 16; ++d) acc += Ea[el * 16 + d] * Ws[d * HH + h];
    ee[(size_t)(e0 + el) * HH + h] = acc;
  }
}

// ---------------- message aggregation (one wave per node, all 4 centroids) --------
// layer 0: x rows are c-major (c*NN+n, harness input); layer 1: n-major (n*CC+c).
// Output h is ALWAYS n-major bf16 hi/lo planes (feeds mlp A-fragments directly).
__global__ __launch_bounds__(256) void agg_kernel(const float* __restrict__ x,
                                                  const float* __restrict__ ee,
                                                  const float* __restrict__ emask,
                                                  const int* __restrict__ src,
                                                  const int* __restrict__ off,
                                                  const int* __restrict__ csr_e,
                                                  const float* __restrict__ epsp, int layer,
                                                  unsigned short* __restrict__ houthi,
                                                  unsigned short* __restrict__ houtlo) {
  int wv = threadIdx.x >> 6, lane = threadIdx.x & 63;
  int v = blockIdx.x * 4 + wv;
  int h2 = lane * 2;
  float2 acc[CC];
#pragma unroll
  for (int c = 0; c < CC; ++c) { acc[c].x = 0.f; acc[c].y = 0.f; }
  int beg = off[v], end = off[v + 1];
  int e = 0, s = 0;
  if (beg < end) { e = csr_e[beg]; s = src[e]; }
  for (int t = beg; t < end; ++t) {
    int tn = t + 1;
    int e2 = 0, s2 = 0;
    if (tn < end) { e2 = csr_e[tn]; s2 = src[e2]; }
    float2 ev = *(const float2*)(ee + (size_t)e * HH + h2);
#pragma unroll
    for (int c = 0; c < CC; ++c) {
      float em = emask[c * EN + e];
      size_t xrow = (layer == 0) ? ((size_t)c * NN + s) : ((size_t)s * CC + c);
      float2 xv = *(const float2*)(x + xrow * HH + h2);
      acc[c].x += gelu_f(xv.x + ev.x) * em;
      acc[c].y += gelu_f(xv.y + ev.y) * em;
    }
    e = e2; s = s2;
  }
  float ep = 1.0f + epsp[layer];
#pragma unroll
  for (int c = 0; c < CC; ++c) {
    size_t srow = (layer == 0) ? ((size_t)c * NN + v) : ((size_t)v * CC + c);
    float2 xs = *(const float2*)(x + srow * HH + h2);
    float ox = ep * xs.x + acc[c].x;
    float oy = ep * xs.y + acc[c].y;
    unsigned short hx = f2bf(ox), hy = f2bf(oy);
    ushort2 hv; hv.x = hx; hv.y = hy;
    ushort2 lv; lv.x = f2bf(ox - bf2f(hx)); lv.y = f2bf(oy - bf2f(hy));
    size_t orow = (size_t)v * CC + c;
    *(ushort2*)(houthi + orow * HH + h2) = hv;
    *(ushort2*)(houtlo + orow * HH + h2) = lv;
  }
}

// ---------------- fused MLP, 64 rows/block, A-frags straight from bf16 planes -----
// mode 0: out = gelu(gelu(in@W1+b1)@W2+b2) -> f32 outf
// mode 1: same, but written as bf16 hi/lo planes (outhi/outlo)
// mode 2: o = gelu(in@W1+b1)@W2+b2; segment-pooled (o * nmask) -> atomicAdd(num)
__global__ __launch_bounds__(256, 2) void mlp_kernel(
    const unsigned short* __restrict__ inhi, const unsigned short* __restrict__ inlo,
    const unsigned short* __restrict__ w1hi, const unsigned short* __restrict__ w1lo,
    const float* __restrict__ b1,
    const unsigned short* __restrict__ w2hi, const unsigned short* __restrict__ w2lo,
    const float* __restrict__ b2,
    float* __restrict__ outf,
    unsigned short* __restrict__ outhi, unsigned short* __restrict__ outlo,
    const float* __restrict__ nmask, const int* __restrict__ batch,
    float* __restrict__ num, int mode) {
  __shared__ __align__(16) unsigned short AB[128 * LDSA];  // t hi rows 0..63, lo rows 64..127
  __shared__ int kk[64];
  unsigned short* Thi = AB;
  unsigned short* Tlo = AB + 64 * LDSA;
  int tid = threadIdx.x;
  int row0 = blockIdx.x * 64;
  int lane = tid & 63, wv = tid >> 6;
  int band = (wv >> 1) * 32;  // 32-row band per wave
  int nh = wv & 1;            // column half
  int ln = lane & 15, quad = lane >> 4;

  // A-fragments directly from global planes (row-major == A-frag order)
  bs8 ahi[2][4], alo[2][4];
#pragma unroll
  for (int mt = 0; mt < 2; ++mt)
#pragma unroll
    for (int ks = 0; ks < 4; ++ks) {
      size_t o = (size_t)(row0 + band + mt * 16 + ln) * HH + ks * 32 + quad * 8;
      ahi[mt][ks] = *(const bs8*)(inhi + o);
      alo[mt][ks] = *(const bs8*)(inlo + o);
    }
  f32x4 acc[2][4];
#pragma unroll
  for (int mt = 0; mt < 2; ++mt)
#pragma unroll
    for (int nt = 0; nt < 4; ++nt)
#pragma unroll
      for (int r = 0; r < 4; ++r) acc[mt][nt][r] = 0.f;
  // GEMM1: 3-term split (a_lo*b_hi + a_hi*b_lo + a_hi*b_hi)
#pragma unroll
  for (int ks = 0; ks < 4; ++ks)
#pragma unroll
    for (int nt = 0; nt < 4; ++nt) {
      int wrow = (nh * 64 + nt * 16 + ln) * HH + ks * 32 + quad * 8;
      bs8 bh = *(const bs8*)(w1hi + wrow);
      bs8 bl = *(const bs8*)(w1lo + wrow);
#pragma unroll
      for (int mt = 0; mt < 2; ++mt) {
        acc[mt][nt] = __builtin_amdgcn_mfma_f32_16x16x32_bf16(alo[mt][ks], bh, acc[mt][nt], 0, 0, 0);
        acc[mt][nt] = __builtin_amdgcn_mfma_f32_16x16x32_bf16(ahi[mt][ks], bl, acc[mt][nt], 0, 0, 0);
        acc[mt][nt] = __builtin_amdgcn_mfma_f32_16x16x32_bf16(ahi[mt][ks], bh, acc[mt][nt], 0, 0, 0);
      }
    }
  // t = gelu(acc + b1) -> LDS hi/lo (disjoint per-wave regions; no barrier before)
#pragma unroll
  for (int nt = 0; nt < 4; ++nt) {
    int col = nh * 64 + nt * 16 + ln;
    float bb = b1[col];
#pragma unroll
    for (int mt = 0; mt < 2; ++mt)
#pragma unroll
      for (int r = 0; r < 4; ++r) {
        float tv = gelu_f(acc[mt][nt][r] + bb);
        unsigned short th = f2bf(tv);
        int rr = band + mt * 16 + quad * 4 + r;
        Thi[rr * LDSA + col] = th;
        Tlo[rr * LDSA + col] = f2bf(tv - bf2f(th));
      }
  }
  __syncthreads();  // B1: t staged
#pragma unroll
  for (int mt = 0; mt < 2; ++mt)
#pragma unroll
    for (int ks = 0; ks < 4; ++ks) {
      ahi[mt][ks] = *(const bs8*)(Thi + (band + mt * 16 + ln) * LDSA + ks * 32 + quad * 8);
      alo[mt][ks] = *(const bs8*)(Tlo + (band + mt * 16 + ln) * LDSA + ks * 32 + quad * 8);
    }
  if (mode == 2) __syncthreads();  // B2: t-frag reads done (LDS reusable for Tf)
#pragma unroll
  for (int mt = 0; mt < 2; ++mt)
#pragma unroll
    for (int nt = 0; nt < 4; ++nt)
#pragma unroll
      for (int r = 0; r < 4; ++r) acc[mt][nt][r] = 0.f;
  // GEMM2
#pragma unroll
  for (int ks = 0; ks < 4; ++ks)
#pragma unroll
    for (int nt = 0; nt < 4; ++nt) {
      int wrow = (nh * 64 + nt * 16 + ln) * HH + ks * 32 + quad * 8;
      bs8 bh = *(const bs8*)(w2hi + wrow);
      bs8 bl = *(const bs8*)(w2lo + wrow);
#pragma unroll
      for (int mt = 0; mt < 2; ++mt) {
        acc[mt][nt] = __builtin_amdgcn_mfma_f32_16x16x32_bf16(alo[mt][ks], bh, acc[mt][nt], 0, 0, 0);
        acc[mt][nt] = __builtin_amdgcn_mfma_f32_16x16x32_bf16(ahi[mt][ks], bl, acc[mt][nt], 0, 0, 0);
        acc[mt][nt] = __builtin_amdgcn_mfma_f32_16x16x32_bf16(ahi[mt][ks], bh, acc[mt][nt], 0, 0, 0);
      }
    }
  if (mode == 0) {
#pragma unroll
    for (int nt = 0; nt < 4; ++nt) {
      int col = nh * 64 + nt * 16 + ln;
      float bb = b2[col];
#pragma unroll
      for (int mt = 0; mt < 2; ++mt)
#pragma unroll
        for (int r = 0; r < 4; ++r) {
          float o = gelu_f(acc[mt][nt][r] + bb);
          outf[(size_t)(row0 + band + mt * 16 + quad * 4 + r) * HH + col] = o;
        }
    }
  } else if (mode == 1) {
#pragma unroll
    for (int nt = 0; nt < 4; ++nt) {
      int col = nh * 64 + nt * 16 + ln;
      float bb = b2[col];
#pragma unroll
      for (int mt = 0; mt < 2; ++mt)
#pragma unroll
        for (int r = 0; r < 4; ++r) {
          float o = gelu_f(acc[mt][nt][r] + bb);
          unsigned short oh = f2bf(o);
          size_t idx = (size_t)(row0 + band + mt * 16 + quad * 4 + r) * HH + col;
          outhi[idx] = oh;
          outlo[idx] = f2bf(o - bf2f(oh));
        }
    }
  } else {
    // fused masked pooling: rows are n-major (n = row>>2, c = row&3), batch sorted
    float* Tf = (float*)AB;
#pragma unroll
    for (int nt = 0; nt < 4; ++nt) {
      int col = nh * 64 + nt * 16 + ln;
      float bb = b2[col];
#pragma unroll
      for (int mt = 0; mt < 2; ++mt)
#pragma unroll
        for (int r = 0; r < 4; ++r) {
          int rl = band + mt * 16 + quad * 4 + r;
          int gr = row0 + rl;
          int n = gr >> 2, c = gr & 3;
          Tf[rl * LDSF + col] = (acc[mt][nt][r] + bb) * nmask[c * NN + n];
        }
    }
    if (tid < 64) {
      int gr = row0 + tid;
      int n = gr >> 2, c = gr & 3;
      kk[tid] = (c << 6) | batch[n];
    }
    __syncthreads();  // B3
    if (tid < 128) {
      int col = tid;
      float a2 = 0.f;
      int cur = kk[0];
      for (int r = 0; r < 64; ++r) {
        int k2 = kk[r];
        if (k2 != cur) {
          atomicAdd(&num[((size_t)(cur & 63) * CC + (cur >> 6)) * HH + col], a2);
          a2 = 0.f;
          cur = k2;
        }
        a2 += Tf[r * LDSF + col];
      }
      atomicAdd(&num[((size_t)(cur & 63) * CC + (cur >> 6)) * HH + col], a2);
    }
  }
}

// ---------------- pool finalize: per-(g,c) den reduce (no atomics) + divide -------
__global__ __launch_bounds__(256) void pool_finalize_kernel(const float* __restrict__ num,
                                                            const int* __restrict__ batch,
                                                            const float* __restrict__ nmask,
                                                            float* __restrict__ outp) {
  int g = blockIdx.x >> 2, c = blockIdx.x & 3;
  int lo = 0, hi = NN;
  while (lo < hi) { int m = (lo + hi) >> 1; if (batch[m] < g) lo = m + 1; else hi = m; }
  int start = lo;
  hi = NN;
  while (lo < hi) { int m = (lo + hi) >> 1; if (batch[m] < g + 1) lo = m + 1; else hi = m; }
  int end = lo;
  int tid = threadIdx.x;
  float d = 0.f;
  for (int n = start + tid; n < end; n += 256) d += nmask[c * NN + n];
#pragma unroll
  for (int k = 1; k < 64; k <<= 1) d += __shfl_xor(d, k);
  __shared__ float ws4[4];
  if ((tid & 63) == 0) ws4[tid >> 6] = d;
  __syncthreads();
  float den = ws4[0] + ws4[1] + ws4[2] + ws4[3] + 1e-7f;
  if (tid < 128) {
    int idx = blockIdx.x * 128 + tid;  // (g*4+c)*128 + col — matches output layout
    outp[idx] = num[idx] / den;
  }
}

extern "C" void kernel_launch(void* const* d_in, const int* in_sizes, int n_in,
                              void* d_out, int out_size, void* d_ws, size_t ws_size,
                              hipStream_t stream) {
  const float* x_in  = (const float*)d_in[0];
  const int*   batch = (const int*)d_in[1];
  const int*   eidx  = (const int*)d_in[2];
  const float* eattr = (const float*)d_in[3];
  const float* nmask = (const float*)d_in[4];
  const float* emask = (const float*)d_in[5];
  const float* Wbe   = (const float*)d_in[6];
  const float* bbe   = (const float*)d_in[7];
  const float* epsp  = (const float*)d_in[8];
  const float* W1    = (const float*)d_in[9];
  const float* b1    = (const float*)d_in[10];
  const float* W2    = (const float*)d_in[11];
  const float* b2    = (const float*)d_in[12];
  const float* Wm1   = (const float*)d_in[13];
  const float* bm1   = (const float*)d_in[14];
  const float* Wm2   = (const float*)d_in[15];
  const float* bm2   = (const float*)d_in[16];
  float* outp = (float*)d_out;

  const int* srcp = eidx;
  const int* dstp = eidx + EN;

  // workspace carve
  char* ws = (char*)d_ws;
  float* ee = (float*)(ws);                              // region A: 102.4 MB
  unsigned short* hhi = (unsigned short*)(ws + 102400000);  // region B: h planes
  unsigned short* hlo = hhi + 25600000;
  float* x1 = (float*)(ws + 204800000);                  // region C: f32 x1 OR x2 planes
  unsigned short* x2hi = (unsigned short*)(ws + 204800000);
  unsigned short* x2lo = x2hi + 25600000;
  int* counts  = (int*)(ws + 307200000);                 // N
  int* offsets = counts + NN;                            // N+1
  int* cursor  = offsets + NN + 1;                       // N
  int* csr_e   = cursor + NN;                            // E
  unsigned short* wts = (unsigned short*)(ws + 307200000 + 1400016);  // 12*16384 bf16
  // temporal overlays in region A:
  int* bsums = (int*)ws;                 // before ee_kernel writes ee
  int* boffs = (int*)(ws + 1024);
  float* num = (float*)ws;               // after last agg read of ee

  const int NB = (NN + 255) / 256;  // 196

  // CSR build
  hipMemsetAsync(counts, 0, NN * sizeof(int), stream);
  count_kernel<<<(EN + 255) / 256, 256, 0, stream>>>(dstp, counts);
  block_sum_kernel<<<NB, 256, 0, stream>>>(counts, bsums);
  bsum_scan_kernel<<<1, 256, 0, stream>>>(bsums, boffs, NB);
  block_scan_kernel<<<NB, 256, 0, stream>>>(counts, boffs, offsets, cursor);
  fill_kernel<<<(EN + 255) / 256, 256, 0, stream>>>(dstp, cursor, csr_e);

  // weight prep (6 matrices in one launch)
  prep_w_kernel<<<384, 256, 0, stream>>>(W1, W2, Wm1, Wm2, wts);

  // bond encoder (overwrites bsums/boffs overlay — stream-ordered after scan)
  ee_kernel<<<EN / 16, 256, 0, stream>>>(eattr, Wbe, bbe, ee);

  // layer 0: agg (c-major input) -> h planes; mlp -> f32 x1 (n-major)
  agg_kernel<<<NN / 4, 256, 0, stream>>>(x_in, ee, emask, srcp, offsets, csr_e, epsp, 0,
                                         hhi, hlo);
  mlp_kernel<<<(CC * NN) / 64, 256, 0, stream>>>(hhi, hlo, wts + 0, wts + 16384, b1,
                                                 wts + 65536, wts + 81920, b2,
                                                 x1, (unsigned short*)nullptr,
                                                 (unsigned short*)nullptr,
                                                 nmask, batch, num, 0);
  // layer 1: agg (n-major input) -> h planes; mlp -> x2 planes
  agg_kernel<<<NN / 4, 256, 0, stream>>>(x1, ee, emask, srcp, offsets, csr_e, epsp, 1,
                                         hhi, hlo);
  hipMemsetAsync(num, 0, 131072, stream);  // ee region dead after agg1
  mlp_kernel<<<(CC * NN) / 64, 256, 0, stream>>>(hhi, hlo, wts + 32768, wts + 49152, b1 + 128,
                                                 wts + 98304, wts + 114688, b2 + 128,
                                                 (float*)nullptr, x2hi, x2lo,
                                                 nmask, batch, num, 1);
  // final node MLP with fused masked-sum pooling
  mlp_kernel<<<(CC * NN) / 64, 256, 0, stream>>>(x2hi, x2lo, wts + 131072, wts + 147456, bm1,
                                                 wts + 163840, wts + 180224, bm2,
                                                 (float*)nullptr, (unsigned short*)nullptr,
                                                 (unsigned short*)nullptr,
                                                 nmask, batch, num, 2);
  // per-(g,c) denominator reduce + divide (no global atomics)
  pool_finalize_kernel<<<GG * CC, 256, 0, stream>>>(num, batch, nmask, outp);
}

// Round 5
// 770.909 us; speedup vs baseline: 1.2416x; 1.2416x over previous
//
#include <hip/hip_runtime.h>
#include <math.h>

#define NN 50000
#define EN 200000
#define CC 4
#define HH 128
#define GG 64
#define LDSA 136  // bf16 row stride (+8 pad keeps 16B alignment, rotates bank groups)
#define LDSF 132  // f32 row stride for fused-pool tile

typedef __attribute__((ext_vector_type(8))) short bs8;
typedef __attribute__((ext_vector_type(4))) float f32x4;

__device__ __forceinline__ unsigned short f2bf(float f) {
  unsigned int u = __float_as_uint(f);
  u += 0x7FFFu + ((u >> 16) & 1u);
  return (unsigned short)(u >> 16);
}
__device__ __forceinline__ float bf2f(unsigned short h) {
  return __uint_as_float(((unsigned int)h) << 16);
}
// fast erf-GELU: A&S 7.1.26 minimax (|erf err| ~1.5e-7) + hw rcp/exp
__device__ __forceinline__ float gelu_f(float x) {
  float z = fabsf(x) * 0.7071067811865476f;
  float t = __builtin_amdgcn_rcpf(fmaf(0.3275911f, z, 1.0f));
  float poly = t * fmaf(t, fmaf(t, fmaf(t, fmaf(t, 1.061405429f, -1.453152027f),
                                        1.421413741f), -0.284496736f), 0.254829592f);
  float e = fmaf(-poly, __expf(-z * z), 1.0f);
  return 0.5f * x * (1.0f + copysignf(e, x));
}

// ---------------- CSR build ----------------
__global__ __launch_bounds__(256) void count_kernel(const int* __restrict__ dst,
                                                    int* __restrict__ counts) {
  int e = blockIdx.x * 256 + threadIdx.x;
  if (e < EN) atomicAdd(&counts[dst[e]], 1);
}

__global__ __launch_bounds__(256) void block_sum_kernel(const int* __restrict__ counts,
                                                        int* __restrict__ bsums) {
  int tid = threadIdx.x;
  int i = blockIdx.x * 256 + tid;
  int v = (i < NN) ? counts[i] : 0;
#pragma unroll
  for (int d = 1; d < 64; d <<= 1) v += __shfl_xor(v, d);
  __shared__ int ws4[4];
  if ((tid & 63) == 0) ws4[tid >> 6] = v;
  __syncthreads();
  if (tid == 0) bsums[blockIdx.x] = ws4[0] + ws4[1] + ws4[2] + ws4[3];
}

__global__ __launch_bounds__(256) void bsum_scan_kernel(const int* __restrict__ bsums,
                                                        int* __restrict__ boffs, int nb) {
  int tid = threadIdx.x, lane = tid & 63, wv = tid >> 6;
  int v = (tid < nb) ? bsums[tid] : 0;
  int s = v;
#pragma unroll
  for (int d = 1; d < 64; d <<= 1) { int t = __shfl_up(s, d); if (lane >= d) s += t; }
  __shared__ int wsum[4];
  if (lane == 63) wsum[wv] = s;
  __syncthreads();
  int pre = 0;
  for (int j = 0; j < wv; ++j) pre += wsum[j];
  if (tid < nb) boffs[tid] = pre + s - v;
}

__global__ __launch_bounds__(256) void block_scan_kernel(const int* __restrict__ counts,
                                                         const int* __restrict__ boffs,
                                                         int* __restrict__ offsets,
                                                         int* __restrict__ cursor) {
  int tid = threadIdx.x, lane = tid & 63, wv = tid >> 6;
  int i = blockIdx.x * 256 + tid;
  int v = (i < NN) ? counts[i] : 0;
  int s = v;
#pragma unroll
  for (int d = 1; d < 64; d <<= 1) { int t = __shfl_up(s, d); if (lane >= d) s += t; }
  __shared__ int wsum[4];
  if (lane == 63) wsum[wv] = s;
  __syncthreads();
  int pre = boffs[blockIdx.x];
  for (int j = 0; j < wv; ++j) pre += wsum[j];
  if (i < NN) { int e = pre + s - v; offsets[i] = e; cursor[i] = e; }
  if (i == 0) offsets[NN] = EN;
}

__global__ __launch_bounds__(256) void fill_kernel(const int* __restrict__ dst,
                                                   int* __restrict__ cursor,
                                                   int* __restrict__ csr_e) {
  int e = blockIdx.x * 256 + threadIdx.x;
  if (e < EN) {
    int pos = atomicAdd(&cursor[dst[e]], 1);
    csr_e[pos] = e;
  }
}

// ---------------- weight prep: transpose + hi/lo bf16 split (all 6 matrices) ------
__global__ __launch_bounds__(256) void prep_w_kernel(const float* __restrict__ W1,
                                                     const float* __restrict__ W2,
                                                     const float* __restrict__ Wm1,
                                                     const float* __restrict__ Wm2,
                                                     unsigned short* __restrict__ wts) {
  int m = blockIdx.x >> 6;
  int idx = (blockIdx.x & 63) * 256 + threadIdx.x;  // 0..16383
  const float* src = (m == 0) ? W1 : (m == 1) ? W1 + 16384 : (m == 2) ? W2
                     : (m == 3) ? W2 + 16384 : (m == 4) ? Wm1 : Wm2;
  unsigned short* dhi = wts + m * 32768;
  unsigned short* dlo = dhi + 16384;
  int n = idx >> 7, k = idx & 127;
  float v = src[k * HH + n];  // src [k][n] -> dst [n][k]
  unsigned short hi = f2bf(v);
  dhi[n * HH + k] = hi;
  dlo[n * HH + k] = f2bf(v - bf2f(hi));
}

// ---------------- bond encoder: 16 edges per block ----------------
__global__ __launch_bounds__(256) void ee_kernel(const float* __restrict__ eattr,
                                                 const float* __restrict__ Wbe,
                                                 const float* __restrict__ bbe,
                                                 float* __restrict__ ee) {
  __shared__ float Ws[16 * HH];
  __shared__ float Ea[16 * 16];
  int tid = threadIdx.x;
  int e0 = blockIdx.x * 16;
#pragma unroll
  for (int i = 0; i < 8; ++i) Ws[tid + i * 256] = Wbe[tid + i * 256];
  Ea[tid] = eattr[(size_t)e0 * 16 + tid];
  __syncthreads();
  int h = tid & 127, half = tid >> 7;
  float bb = bbe[h];
#pragma unroll
  for (int j = 0; j < 8; ++j) {
    int el = j * 2 + half;
    float acc = bb;
#pragma unroll
    for (int d = 0; d < 16; ++d) acc += Ea[el * 16 + d] * Ws[d * HH + h];
    ee[(size_t)(e0 + el) * HH + h] = acc;
  }
}

// ---------------- message aggregation (one wave per node, all 4 centroids) --------
__global__ __launch_bounds__(256) void agg_kernel(const float* __restrict__ x,
                                                  const float* __restrict__ ee,
                                                  const float* __restrict__ emask,
                                                  const int* __restrict__ src,
                                                  const int* __restrict__ off,
                                                  const int* __restrict__ csr_e,
                                                  const float* __restrict__ epsp, int layer,
                                                  float* __restrict__ hout) {
  int wv = threadIdx.x >> 6, lane = threadIdx.x & 63;
  int v = blockIdx.x * 4 + wv;
  int h2 = lane * 2;
  float2 acc[CC];
#pragma unroll
  for (int c = 0; c < CC; ++c) { acc[c].x = 0.f; acc[c].y = 0.f; }
  int beg = off[v], end = off[v + 1];
  int e = 0, s = 0;
  if (beg < end) { e = csr_e[beg]; s = src[e]; }
  for (int t = beg; t < end; ++t) {
    int tn = t + 1;
    int e2 = 0, s2 = 0;
    if (tn < end) { e2 = csr_e[tn]; s2 = src[e2]; }
    float2 ev = *(const float2*)(ee + (size_t)e * HH + h2);
#pragma unroll
    for (int c = 0; c < CC; ++c) {
      float em = emask[c * EN + e];
      float2 xv = *(const float2*)(x + (size_t)(c * NN + s) * HH + h2);
      acc[c].x += gelu_f(xv.x + ev.x) * em;
      acc[c].y += gelu_f(xv.y + ev.y) * em;
    }
    e = e2; s = s2;
  }
  float ep = 1.0f + epsp[layer];
#pragma unroll
  for (int c = 0; c < CC; ++c) {
    float2 xs = *(const float2*)(x + (size_t)(c * NN + v) * HH + h2);
    float2 o;
    o.x = ep * xs.x + acc[c].x;
    o.y = ep * xs.y + acc[c].y;
    *(float2*)(hout + (size_t)(c * NN + v) * HH + h2) = o;
  }
}

// ---------------- fused MLP, 64 rows/block ----------------
// Wave layout: each wave owns a 32-col quarter x all 64 rows (B-frag reuse x12 MFMA).
// W fragments preloaded into registers (16-deep MLP) before barriers hide their latency.
// mode 0: out = gelu(gelu(in@W1+b1)@W2+b2) -> f32 out
// mode 1: o = gelu(in@W1+b1)@W2+b2; segment-pooled (o * nmask) -> atomicAdd(num)
__global__ __launch_bounds__(256, 2) void mlp_kernel(
    const float* __restrict__ in,
    const unsigned short* __restrict__ w1hi, const unsigned short* __restrict__ w1lo,
    const float* __restrict__ b1,
    const unsigned short* __restrict__ w2hi, const unsigned short* __restrict__ w2lo,
    const float* __restrict__ b2,
    float* __restrict__ out,
    const float* __restrict__ nmask, const int* __restrict__ batch,
    float* __restrict__ num, int mode) {
  __shared__ __align__(16) unsigned short AB[128 * LDSA];  // hi rows 0..63, lo rows 64..127
  __shared__ int kk[64];
  unsigned short* Ahi = AB;
  unsigned short* Alo = AB + 64 * LDSA;
  int tid = threadIdx.x;
  int row0 = blockIdx.x * 64;
  int lane = tid & 63, wq = tid >> 6;  // wq = column quarter
  int ln = lane & 15, quad = lane >> 4;

  // Preload ALL GEMM1 B-fragments (16 x 16B global loads, issued back-to-back;
  // latency overlaps stage-A conversion + barrier below).
  bs8 b1h[4][2], b1l[4][2];
#pragma unroll
  for (int ks = 0; ks < 4; ++ks)
#pragma unroll
    for (int nt = 0; nt < 2; ++nt) {
      int wrow = ((wq * 2 + nt) * 16 + ln) * HH + ks * 32 + quad * 8;
      b1h[ks][nt] = *(const bs8*)(w1hi + wrow);
      b1l[ks][nt] = *(const bs8*)(w1lo + wrow);
    }

  // stage A: 64 rows x 128 f32 -> hi/lo bf16 (fully coalesced float4 loads)
#pragma unroll
  for (int i = 0; i < 8; ++i) {
    int idx = tid + i * 256;  // 2048 float4 chunks
    int r = idx >> 5, c4 = idx & 31;
    float4 vv = *(const float4*)(in + (size_t)(row0 + r) * HH + c4 * 4);
    unsigned short h0 = f2bf(vv.x), h1 = f2bf(vv.y), h2 = f2bf(vv.z), h3 = f2bf(vv.w);
    ushort4 hv; hv.x = h0; hv.y = h1; hv.z = h2; hv.w = h3;
    ushort4 lv;
    lv.x = f2bf(vv.x - bf2f(h0)); lv.y = f2bf(vv.y - bf2f(h1));
    lv.z = f2bf(vv.z - bf2f(h2)); lv.w = f2bf(vv.w - bf2f(h3));
    *(ushort4*)(Ahi + r * LDSA + c4 * 4) = hv;
    *(ushort4*)(Alo + r * LDSA + c4 * 4) = lv;
  }
  __syncthreads();  // B1: A staged

  f32x4 acc[4][2];
#pragma unroll
  for (int mt = 0; mt < 4; ++mt)
#pragma unroll
    for (int nt = 0; nt < 2; ++nt)
#pragma unroll
      for (int r = 0; r < 4; ++r) acc[mt][nt][r] = 0.f;
  // GEMM1: A-frags stream from LDS per ks; 3-term split
#pragma unroll
  for (int ks = 0; ks < 4; ++ks) {
    bs8 ah[4], al[4];
#pragma unroll
    for (int mt = 0; mt < 4; ++mt) {
      ah[mt] = *(const bs8*)(Ahi + (mt * 16 + ln) * LDSA + ks * 32 + quad * 8);
      al[mt] = *(const bs8*)(Alo + (mt * 16 + ln) * LDSA + ks * 32 + quad * 8);
    }
#pragma unroll
    for (int nt = 0; nt < 2; ++nt)
#pragma unroll
      for (int mt = 0; mt < 4; ++mt) {
        acc[mt][nt] = __builtin_amdgcn_mfma_f32_16x16x32_bf16(al[mt], b1h[ks][nt], acc[mt][nt], 0, 0, 0);
        acc[mt][nt] = __builtin_amdgcn_mfma_f32_16x16x32_bf16(ah[mt], b1l[ks][nt], acc[mt][nt], 0, 0, 0);
        acc[mt][nt] = __builtin_amdgcn_mfma_f32_16x16x32_bf16(ah[mt], b1h[ks][nt], acc[mt][nt], 0, 0, 0);
      }
  }
  __syncthreads();  // B2: all A-frag reads done (LDS reusable for t)

  // Preload GEMM2 B-fragments now — latency overlaps t-stage VALU + B3 barrier.
  bs8 b2h[4][2], b2l[4][2];
#pragma unroll
  for (int ks = 0; ks < 4; ++ks)
#pragma unroll
    for (int nt = 0; nt < 2; ++nt) {
      int wrow = ((wq * 2 + nt) * 16 + ln) * HH + ks * 32 + quad * 8;
      b2h[ks][nt] = *(const bs8*)(w2hi + wrow);
      b2l[ks][nt] = *(const bs8*)(w2lo + wrow);
    }

  // t = gelu(acc + b1) -> LDS hi/lo (each wave writes its 32-col quarter, all rows)
#pragma unroll
  for (int nt = 0; nt < 2; ++nt) {
    int col = (wq * 2 + nt) * 16 + ln;
    float bb = b1[col];
#pragma unroll
    for (int mt = 0; mt < 4; ++mt)
#pragma unroll
      for (int r = 0; r < 4; ++r) {
        float tv = gelu_f(acc[mt][nt][r] + bb);
        unsigned short th = f2bf(tv);
        int rr = mt * 16 + quad * 4 + r;
        Ahi[rr * LDSA + col] = th;
        Alo[rr * LDSA + col] = f2bf(tv - bf2f(th));
      }
  }
  __syncthreads();  // B3: t staged

#pragma unroll
  for (int mt = 0; mt < 4; ++mt)
#pragma unroll
    for (int nt = 0; nt < 2; ++nt)
#pragma unroll
      for (int r = 0; r < 4; ++r) acc[mt][nt][r] = 0.f;
  // GEMM2
  if (mode == 0) {
#pragma unroll
    for (int ks = 0; ks < 4; ++ks) {
      bs8 ah[4], al[4];
#pragma unroll
      for (int mt = 0; mt < 4; ++mt) {
        ah[mt] = *(const bs8*)(Ahi + (mt * 16 + ln) * LDSA + ks * 32 + quad * 8);
        al[mt] = *(const bs8*)(Alo + (mt * 16 + ln) * LDSA + ks * 32 + quad * 8);
      }
#pragma unroll
      for (int nt = 0; nt < 2; ++nt)
#pragma unroll
        for (int mt = 0; mt < 4; ++mt) {
          acc[mt][nt] = __builtin_amdgcn_mfma_f32_16x16x32_bf16(al[mt], b2h[ks][nt], acc[mt][nt], 0, 0, 0);
          acc[mt][nt] = __builtin_amdgcn_mfma_f32_16x16x32_bf16(ah[mt], b2l[ks][nt], acc[mt][nt], 0, 0, 0);
          acc[mt][nt] = __builtin_amdgcn_mfma_f32_16x16x32_bf16(ah[mt], b2h[ks][nt], acc[mt][nt], 0, 0, 0);
        }
    }
#pragma unroll
    for (int nt = 0; nt < 2; ++nt) {
      int col = (wq * 2 + nt) * 16 + ln;
      float bb = b2[col];
#pragma unroll
      for (int mt = 0; mt < 4; ++mt)
#pragma unroll
        for (int r = 0; r < 4; ++r) {
          float o = gelu_f(acc[mt][nt][r] + bb);
          out[(size_t)(row0 + mt * 16 + quad * 4 + r) * HH + col] = o;
        }
    }
  } else {
    // GEMM2 with all t-frag reads completed before Tf overwrites LDS
#pragma unroll
    for (int ks = 0; ks < 4; ++ks) {
      bs8 ah[4], al[4];
#pragma unroll
      for (int mt = 0; mt < 4; ++mt) {
        ah[mt] = *(const bs8*)(Ahi + (mt * 16 + ln) * LDSA + ks * 32 + quad * 8);
        al[mt] = *(const bs8*)(Alo + (mt * 16 + ln) * LDSA + ks * 32 + quad * 8);
      }
#pragma unroll
      for (int nt = 0; nt < 2; ++nt)
#pragma unroll
        for (int mt = 0; mt < 4; ++mt) {
          acc[mt][nt] = __builtin_amdgcn_mfma_f32_16x16x32_bf16(al[mt], b2h[ks][nt], acc[mt][nt], 0, 0, 0);
          acc[mt][nt] = __builtin_amdgcn_mfma_f32_16x16x32_bf16(ah[mt], b2l[ks][nt], acc[mt][nt], 0, 0, 0);
          acc[mt][nt] = __builtin_amdgcn_mfma_f32_16x16x32_bf16(ah[mt], b2h[ks][nt], acc[mt][nt], 0, 0, 0);
        }
    }
    __syncthreads();  // B4: t-frag reads done (LDS reusable for Tf)
    // fused masked pooling: rows c-major (row = c*NN + n), batch sorted
    float* Tf = (float*)AB;
#pragma unroll
    for (int nt = 0; nt < 2; ++nt) {
      int col = (wq * 2 + nt) * 16 + ln;
      float bb = b2[col];
#pragma unroll
      for (int mt = 0; mt < 4; ++mt)
#pragma unroll
        for (int r = 0; r < 4; ++r) {
          int rl = mt * 16 + quad * 4 + r;
          int gr = row0 + rl;
          Tf[rl * LDSF + col] = (acc[mt][nt][r] + bb) * nmask[gr];
        }
    }
    if (tid < 64) {
      int gr = row0 + tid;
      int c = gr / NN;
      int n = gr - c * NN;
      kk[tid] = (c << 6) | batch[n];
    }
    __syncthreads();  // B5
    if (tid < 128) {
      int col = tid;
      float a2 = 0.f;
      int cur = kk[0];
      for (int r = 0; r < 64; ++r) {
        int k2 = kk[r];
        if (k2 != cur) {
          atomicAdd(&num[((size_t)(cur & 63) * CC + (cur >> 6)) * HH + col], a2);
          a2 = 0.f;
          cur = k2;
        }
        a2 += Tf[r * LDSF + col];
      }
      atomicAdd(&num[((size_t)(cur & 63) * CC + (cur >> 6)) * HH + col], a2);
    }
  }
}

// ---------------- pool finalize: per-(g,c) den reduce (no atomics) + divide -------
__global__ __launch_bounds__(256) void pool_finalize_kernel(const float* __restrict__ num,
                                                            const int* __restrict__ batch,
                                                            const float* __restrict__ nmask,
                                                            float* __restrict__ outp) {
  int g = blockIdx.x >> 2, c = blockIdx.x & 3;
  int lo = 0, hi = NN;
  while (lo < hi) { int m = (lo + hi) >> 1; if (batch[m] < g) lo = m + 1; else hi = m; }
  int start = lo;
  hi = NN;
  while (lo < hi) { int m = (lo + hi) >> 1; if (batch[m] < g + 1) lo = m + 1; else hi = m; }
  int end = lo;
  int tid = threadIdx.x;
  float d = 0.f;
  for (int n = start + tid; n < end; n += 256) d += nmask[c * NN + n];
#pragma unroll
  for (int k = 1; k < 64; k <<= 1) d += __shfl_xor(d, k);
  __shared__ float ws4[4];
  if ((tid & 63) == 0) ws4[tid >> 6] = d;
  __syncthreads();
  float den = ws4[0] + ws4[1] + ws4[2] + ws4[3] + 1e-7f;
  if (tid < 128) {
    int idx = blockIdx.x * 128 + tid;  // (g*4+c)*128 + col — matches output layout
    outp[idx] = num[idx] / den;
  }
}

extern "C" void kernel_launch(void* const* d_in, const int* in_sizes, int n_in,
                              void* d_out, int out_size, void* d_ws, size_t ws_size,
                              hipStream_t stream) {
  const float* x_in  = (const float*)d_in[0];
  const int*   batch = (const int*)d_in[1];
  const int*   eidx  = (const int*)d_in[2];
  const float* eattr = (const float*)d_in[3];
  const float* nmask = (const float*)d_in[4];
  const float* emask = (const float*)d_in[5];
  const float* Wbe   = (const float*)d_in[6];
  const float* bbe   = (const float*)d_in[7];
  const float* epsp  = (const float*)d_in[8];
  const float* W1    = (const float*)d_in[9];
  const float* b1    = (const float*)d_in[10];
  const float* W2    = (const float*)d_in[11];
  const float* b2    = (const float*)d_in[12];
  const float* Wm1   = (const float*)d_in[13];
  const float* bm1   = (const float*)d_in[14];
  const float* Wm2   = (const float*)d_in[15];
  const float* bm2   = (const float*)d_in[16];
  float* outp = (float*)d_out;

  const int* srcp = eidx;
  const int* dstp = eidx + EN;

  // workspace carve
  char* ws = (char*)d_ws;
  float* ee   = (float*)(ws);                  // 102,400,000 B
  float* hbuf = (float*)(ws + 102400000);
  float* xbuf = (float*)(ws + 204800000);
  int* counts  = (int*)(ws + 307200000);       // N
  int* offsets = counts + NN;                  // N+1
  int* cursor  = offsets + NN + 1;             // N
  int* csr_e   = cursor + NN;                  // E
  unsigned short* wts = (unsigned short*)(ws + 307200000 + 1400016);  // 12*16384 bf16
  // temporal overlays in the ee region:
  int* bsums = (int*)ws;                 // before ee_kernel writes ee
  int* boffs = (int*)(ws + 1024);
  float* num = (float*)ws;               // after last agg read of ee

  const int NB = (NN + 255) / 256;  // 196

  // CSR build
  hipMemsetAsync(counts, 0, NN * sizeof(int), stream);
  count_kernel<<<(EN + 255) / 256, 256, 0, stream>>>(dstp, counts);
  block_sum_kernel<<<NB, 256, 0, stream>>>(counts, bsums);
  bsum_scan_kernel<<<1, 256, 0, stream>>>(bsums, boffs, NB);
  block_scan_kernel<<<NB, 256, 0, stream>>>(counts, boffs, offsets, cursor);
  fill_kernel<<<(EN + 255) / 256, 256, 0, stream>>>(dstp, cursor, csr_e);

  // weight prep (6 matrices in one launch)
  prep_w_kernel<<<384, 256, 0, stream>>>(W1, W2, Wm1, Wm2, wts);

  // bond encoder (overwrites bsums/boffs overlay — stream-ordered after scan)
  ee_kernel<<<EN / 16, 256, 0, stream>>>(eattr, Wbe, bbe, ee);

  // layer 0
  agg_kernel<<<NN / 4, 256, 0, stream>>>(x_in, ee, emask, srcp, offsets, csr_e, epsp, 0, hbuf);
  mlp_kernel<<<(CC * NN) / 64, 256, 0, stream>>>(hbuf, wts + 0, wts + 16384, b1,
                                                 wts + 65536, wts + 81920, b2,
                                                 xbuf, nmask, batch, num, 0);
  // layer 1
  agg_kernel<<<NN / 4, 256, 0, stream>>>(xbuf, ee, emask, srcp, offsets, csr_e, epsp, 1, hbuf);
  mlp_kernel<<<(CC * NN) / 64, 256, 0, stream>>>(hbuf, wts + 32768, wts + 49152, b1 + 128,
                                                 wts + 98304, wts + 114688, b2 + 128,
                                                 xbuf, nmask, batch, num, 0);
  // final node MLP with fused masked-sum pooling (ee dead -> num overlay live)
  hipMemsetAsync(num, 0, 131072, stream);
  mlp_kernel<<<(CC * NN) / 64, 256, 0, stream>>>(xbuf, wts + 131072, wts + 147456, bm1,
                                                 wts + 163840, wts + 180224, bm2,
                                                 (float*)nullptr, nmask, batch, num, 1);
  // per-(g,c) denominator reduce + divide (no global atomics)
  pool_finalize_kernel<<<GG * CC, 256, 0, stream>>>(num, batch, nmask, outp);
}